// Round 8
// baseline (3153.776 us; speedup 1.0000x reference)
//
#include <hip/hip_runtime.h>
#include <hip/hip_cooperative_groups.h>

namespace cg = cooperative_groups;

// Problem constants (match reference)
static constexpr int DIM = 128;
static constexpr int N = DIM * DIM * DIM;        // 2,097,152 voxels
static constexpr int ITERS = 20;
static constexpr float EPS = 1e-6f;

// Gaussian(sigma=1, radius=3) normalized weights
#define W0 0.39905028f
#define W1 0.24203624f
#define W2 0.05400559f
#define W3 0.00443305f

__device__ __forceinline__ int clamp_i(int v, int lo, int hi) {
    return min(max(v, lo), hi);
}

#define ROWS 22            // 16 + 2*3 halo
#define SC(c, r) ((((c) * ROWS) + (r)) << 7)

// ---------------------------------------------------------------------------
// Persistent cooperative kernel: 20 iterations in one launch.
// Phase A (per 1024 tiles: z-plane x 16-row y-strip): forces (all 3 channels,
// once per voxel) -> LDS, x-blur in LDS (per-channel to cap VGPR), y-blur ->
// u2.  grid.sync().  Phase B (per column x 8-z chunk): z-blur 3 channels in
// registers -> vf, then next iteration's trilinear warp from registers ->
// warped.  grid.sync().
// LDS 33792 B; __launch_bounds__(256,4) caps VGPR at 128 -> 4 blocks/CU.
// ---------------------------------------------------------------------------
__global__ __launch_bounds__(256, 4) void varreg_persistent(
        const float* __restrict__ mov, const float* __restrict__ fix,
        float* __restrict__ vf, float* __restrict__ warped,
        float* __restrict__ u2) {
    cg::grid_group grid = cg::this_grid();
    __shared__ float S[3 * ROWS * 128];
    const int tid = threadIdx.x;

    for (int iter = 0; iter < ITERS; ++iter) {
        const bool first = (iter == 0);
        const float* wpd = first ? mov : warped;

        // ================= Phase A: forces + x-blur + y-blur =================
        for (int tile = blockIdx.x; tile < 1024; tile += gridDim.x) {
            int z = tile & 127;
            int y0 = (tile >> 7) << 4;

            // ---- Stage A: forces (one eval/voxel, all channels) -> S
            for (int e = tid; e < ROWS * 32; e += 256) {
                int x4 = e & 31;
                int r  = e >> 5;
                int gy = y0 + r - 3;
                float4 rz = make_float4(0, 0, 0, 0);
                float4 ry = make_float4(0, 0, 0, 0);
                float4 rx = make_float4(0, 0, 0, 0);
                if (gy >= 0 && gy < 128) {
                    int idx = (z << 14) + (gy << 7) + (x4 << 2);
                    int xb = x4 << 2;

                    float4 wc4 = *(const float4*)(wpd + idx);
                    float4 fc4 = *(const float4*)(fix + idx);

                    int iyp = (gy < 127) ? idx + 128   : idx;
                    int iym = (gy > 0)   ? idx - 128   : idx;
                    int izp = (z < 127)  ? idx + 16384 : idx;
                    int izm = (z > 0)    ? idx - 16384 : idx;

                    float4 wyp = *(const float4*)(wpd + iyp), wym = *(const float4*)(wpd + iym);
                    float4 wzp = *(const float4*)(wpd + izp), wzm = *(const float4*)(wpd + izm);
                    float4 fyp = *(const float4*)(fix + iyp), fym = *(const float4*)(fix + iym);
                    float4 fzp = *(const float4*)(fix + izp), fzm = *(const float4*)(fix + izm);

                    float wl = (xb > 0)   ? wpd[idx - 1] : 0.0f;
                    float wr = (xb < 124) ? wpd[idx + 4] : 0.0f;
                    float fl = (xb > 0)   ? fix[idx - 1] : 0.0f;
                    float fr = (xb < 124) ? fix[idx + 4] : 0.0f;

                    float wcv[4] = {wc4.x, wc4.y, wc4.z, wc4.w};
                    float fcv[4] = {fc4.x, fc4.y, fc4.z, fc4.w};
                    float wypv[4] = {wyp.x, wyp.y, wyp.z, wyp.w};
                    float wymv[4] = {wym.x, wym.y, wym.z, wym.w};
                    float wzpv[4] = {wzp.x, wzp.y, wzp.z, wzp.w};
                    float wzmv[4] = {wzm.x, wzm.y, wzm.z, wzm.w};
                    float fypv[4] = {fyp.x, fyp.y, fyp.z, fyp.w};
                    float fymv[4] = {fym.x, fym.y, fym.z, fym.w};
                    float fzpv[4] = {fzp.x, fzp.y, fzp.z, fzp.w};
                    float fzmv[4] = {fzm.x, fzm.y, fzm.z, fzm.w};

                    float4 vz4 = first ? make_float4(0, 0, 0, 0) : *(const float4*)(vf + idx);
                    float4 vy4 = first ? make_float4(0, 0, 0, 0) : *(const float4*)(vf + N + idx);
                    float4 vx4 = first ? make_float4(0, 0, 0, 0) : *(const float4*)(vf + 2 * N + idx);
                    float vzv[4] = {vz4.x, vz4.y, vz4.z, vz4.w};
                    float vyv[4] = {vy4.x, vy4.y, vy4.z, vy4.w};
                    float vxv[4] = {vx4.x, vx4.y, vx4.z, vx4.w};

                    float ozv[4], oyv[4], oxv[4];
#pragma unroll
                    for (int i = 0; i < 4; ++i) {
                        float wc = wcv[i], fc = fcv[i];
                        float diff = wc - fc;

                        float gwz = (z == 0)   ? (wzpv[i] - wc)
                                  : (z == 127) ? (wc - wzmv[i])
                                  : 0.5f * (wzpv[i] - wzmv[i]);
                        float gfz = (z == 0)   ? (fzpv[i] - fc)
                                  : (z == 127) ? (fc - fzmv[i])
                                  : 0.5f * (fzpv[i] - fzmv[i]);
                        float grz = 0.5f * (gwz + gfz);

                        float gwy = (gy == 0)   ? (wypv[i] - wc)
                                  : (gy == 127) ? (wc - wymv[i])
                                  : 0.5f * (wypv[i] - wymv[i]);
                        float gfy = (gy == 0)   ? (fypv[i] - fc)
                                  : (gy == 127) ? (fc - fymv[i])
                                  : 0.5f * (fypv[i] - fymv[i]);
                        float gry = 0.5f * (gwy + gfy);

                        float wleft  = (i == 0) ? wl : wcv[i - 1];
                        float wright = (i == 3) ? wr : wcv[i + 1];
                        float fleft  = (i == 0) ? fl : fcv[i - 1];
                        float fright = (i == 3) ? fr : fcv[i + 1];
                        int xi = xb + i;
                        float gwx = (xi == 0)   ? (wright - wc)
                                  : (xi == 127) ? (wc - wleft)
                                  : 0.5f * (wright - wleft);
                        float gfx = (xi == 0)   ? (fright - fc)
                                  : (xi == 127) ? (fc - fleft)
                                  : 0.5f * (fright - fleft);
                        float grx = 0.5f * (gwx + gfx);

                        float denom = grz * grz + gry * gry + grx * grx + diff * diff;
                        float s = (denom > EPS) ? (diff / denom) : 0.0f;
                        ozv[i] = vzv[i] + s * grz;
                        oyv[i] = vyv[i] + s * gry;
                        oxv[i] = vxv[i] + s * grx;
                    }
                    rz = make_float4(ozv[0], ozv[1], ozv[2], ozv[3]);
                    ry = make_float4(oyv[0], oyv[1], oyv[2], oyv[3]);
                    rx = make_float4(oxv[0], oxv[1], oxv[2], oxv[3]);
                }
                *(float4*)(S + SC(0, r) + (x4 << 2)) = rz;
                *(float4*)(S + SC(1, r) + (x4 << 2)) = ry;
                *(float4*)(S + SC(2, r) + (x4 << 2)) = rx;
            }
            __syncthreads();

            // ---- Stage B: x-blur, in-place LDS rewrite, one channel at a
            //      time (12 regs held across barrier instead of 36)
#pragma unroll
            for (int c = 0; c < 3; ++c) {
                float4 xbv[3];
#pragma unroll
                for (int it2 = 0; it2 < 3; ++it2) {
                    int e = tid + it2 * 256;
                    if (e < ROWS * 32) {
                        int x4 = e & 31;
                        int r  = e >> 5;
                        const float* base = S + SC(c, r) + (x4 << 2);
                        float4 v0 = *(const float4*)base;
                        float4 m1 = (x4 > 0)  ? *(const float4*)(base - 4) : make_float4(0, 0, 0, 0);
                        float4 p1 = (x4 < 31) ? *(const float4*)(base + 4) : make_float4(0, 0, 0, 0);
                        float w[12] = {m1.x, m1.y, m1.z, m1.w,
                                       v0.x, v0.y, v0.z, v0.w,
                                       p1.x, p1.y, p1.z, p1.w};
                        float o[4];
#pragma unroll
                        for (int i = 0; i < 4; ++i) {
                            o[i] = W3 * (w[i + 1] + w[i + 7]) + W2 * (w[i + 2] + w[i + 6])
                                 + W1 * (w[i + 3] + w[i + 5]) + W0 * w[i + 4];
                        }
                        xbv[it2] = make_float4(o[0], o[1], o[2], o[3]);
                    }
                }
                __syncthreads();
#pragma unroll
                for (int it2 = 0; it2 < 3; ++it2) {
                    int e = tid + it2 * 256;
                    if (e < ROWS * 32) {
                        int x4 = e & 31;
                        int r  = e >> 5;
                        *(float4*)(S + SC(c, r) + (x4 << 2)) = xbv[it2];
                    }
                }
                __syncthreads();
            }

            // ---- Stage C: y-blur S -> global u2
            for (int e = tid; e < 16 * 32 * 3; e += 256) {
                int x4 = e & 31;
                int t2 = e >> 5;
                int y  = t2 & 15;
                int c  = t2 >> 4;
                const float* base = S + SC(c, y) + (x4 << 2);
                float4 v0 = *(const float4*)(base);
                float4 v1 = *(const float4*)(base + (1 << 7));
                float4 v2 = *(const float4*)(base + (2 << 7));
                float4 v3 = *(const float4*)(base + (3 << 7));
                float4 v4 = *(const float4*)(base + (4 << 7));
                float4 v5 = *(const float4*)(base + (5 << 7));
                float4 v6 = *(const float4*)(base + (6 << 7));
                float4 acc;
                acc.x = W3 * (v0.x + v6.x) + W2 * (v1.x + v5.x) + W1 * (v2.x + v4.x) + W0 * v3.x;
                acc.y = W3 * (v0.y + v6.y) + W2 * (v1.y + v5.y) + W1 * (v2.y + v4.y) + W0 * v3.y;
                acc.z = W3 * (v0.z + v6.z) + W2 * (v1.z + v5.z) + W1 * (v2.z + v4.z) + W0 * v3.z;
                acc.w = W3 * (v0.w + v6.w) + W2 * (v1.w + v5.w) + W1 * (v2.w + v4.w) + W0 * v3.w;
                *(float4*)(u2 + (size_t)c * N + ((size_t)z << 14) + ((y0 + y) << 7) + (x4 << 2)) = acc;
            }
            __syncthreads();   // protect S before next tile's Stage A
        }

        grid.sync();

        // ================= Phase B: z-blur + next warp =================
        const bool do_warp = (iter < ITERS - 1);
        for (int g = blockIdx.x * 256 + tid; g < 262144; g += gridDim.x * 256) {
            int col = g & 16383;              // (y<<7)|x
            int zc  = g >> 14;                // 0..15
            int z0  = zc << 3;
            int x = col & 127, y = col >> 7;

            float bz[3][8];
#pragma unroll
            for (int c = 0; c < 3; ++c) {
                const float* inp = u2 + (size_t)c * N + col;
                float win[14];
#pragma unroll
                for (int i = 0; i < 14; ++i) {
                    int zz = z0 - 3 + i;
                    win[i] = (zz >= 0 && zz < 128) ? inp[(size_t)zz << 14] : 0.0f;
                }
#pragma unroll
                for (int k = 0; k < 8; ++k) {
                    bz[c][k] = W3 * (win[k] + win[k + 6]) + W2 * (win[k + 1] + win[k + 5])
                             + W1 * (win[k + 2] + win[k + 4]) + W0 * win[k + 3];
                }
                float* outp = vf + (size_t)c * N + col;
#pragma unroll
                for (int k = 0; k < 8; ++k)
                    outp[(size_t)(z0 + k) << 14] = bz[c][k];
            }

            if (do_warp) {
                for (int k = 0; k < 8; ++k) {
                    int z = z0 + k;
                    float cz = (float)z + bz[0][k];
                    float cy = (float)y + bz[1][k];
                    float cx = (float)x + bz[2][k];

                    float flz = floorf(cz), fly = floorf(cy), flx = floorf(cx);
                    float fz = cz - flz, fy = cy - fly, fx = cx - flx;

                    int zi = (int)flz, yi = (int)fly, xi = (int)flx;
                    int z0c = clamp_i(zi, 0, DIM - 1), z1c = clamp_i(zi + 1, 0, DIM - 1);
                    int y0c = clamp_i(yi, 0, DIM - 1), y1c = clamp_i(yi + 1, 0, DIM - 1);
                    int x0c = clamp_i(xi, 0, DIM - 1), x1c = clamp_i(xi + 1, 0, DIM - 1);

                    int b00 = (z0c << 14) + (y0c << 7);
                    int b01 = (z0c << 14) + (y1c << 7);
                    int b10 = (z1c << 14) + (y0c << 7);
                    int b11 = (z1c << 14) + (y1c << 7);

                    float v000 = mov[b00 + x0c], v001 = mov[b00 + x1c];
                    float v010 = mov[b01 + x0c], v011 = mov[b01 + x1c];
                    float v100 = mov[b10 + x0c], v101 = mov[b10 + x1c];
                    float v110 = mov[b11 + x0c], v111 = mov[b11 + x1c];

                    float c00 = v000 + fx * (v001 - v000);
                    float c01 = v010 + fx * (v011 - v010);
                    float c10 = v100 + fx * (v101 - v100);
                    float c11 = v110 + fx * (v111 - v110);
                    float c0 = c00 + fy * (c01 - c00);
                    float c1 = c10 + fy * (c11 - c10);
                    warped[((size_t)z << 14) + col] = c0 + fz * (c1 - c0);
                }
            }
        }

        grid.sync();
    }
}

extern "C" void kernel_launch(void* const* d_in, const int* in_sizes, int n_in,
                              void* d_out, int out_size, void* d_ws, size_t ws_size,
                              hipStream_t stream) {
    const float* mov = (const float*)d_in[0];
    const float* fix = (const float*)d_in[1];
    float* vf = (float*)d_out;          // (3, N) — fully written each iteration
    float* ws = (float*)d_ws;
    float* warped = ws;                 // N floats
    float* u2     = ws + (size_t)N;     // 3N floats (xy-blurred forces)

    // Size grid to guaranteed co-residency (grid-stride loops keep any
    // grid size correct). Pure occupancy query — no stream ops, graph-safe.
    int maxBlocksPerCU = 0;
    hipOccupancyMaxActiveBlocksPerMultiprocessor(&maxBlocksPerCU,
        (const void*)varreg_persistent, 256, 0);
    if (maxBlocksPerCU < 1) maxBlocksPerCU = 1;
    int grid = maxBlocksPerCU * 256;    // 256 CUs on MI355X
    if (grid > 1024) grid = 1024;

    void* args[] = {(void*)&mov, (void*)&fix, (void*)&vf, (void*)&warped, (void*)&u2};
    hipLaunchCooperativeKernel((const void*)varreg_persistent,
                               dim3(grid), dim3(256), args, 0, stream);
}

// Round 9
// 877.721 us; speedup vs baseline: 3.5931x; 3.5931x over previous
//
#include <hip/hip_runtime.h>

// Problem constants (match reference)
static constexpr int DIM = 128;
static constexpr int N = DIM * DIM * DIM;        // 2,097,152 voxels
static constexpr int ITERS = 20;
static constexpr float EPS = 1e-6f;

// Gaussian(sigma=1, radius=3) normalized weights
#define W0 0.39905028f
#define W1 0.24203624f
#define W2 0.05400559f
#define W3 0.00443305f

__device__ __forceinline__ int clamp_i(int v, int lo, int hi) {
    return min(max(v, lo), hi);
}

// ---------------------------------------------------------------------------
// Fused forces (ALL 3 channels, computed ONCE per voxel) + x-blur + y-blur.
// One block per (z-plane, 16-row y-strip). Stage A: forces for the 22-row
// halo strip -> LDS S[3][22][132] (row stride padded 128->132 floats = +4
// banks/row to kill the half-wave bank aliasing measured in R8:
// SQ_LDS_BANK_CONFLICT 2.57e7/20iter). Stage B: x-blur via register-held
// in-place LDS rewrite. Stage C: y-blur -> global u2. u never materialized.
// LDS = 3*22*132*4 = 34848 B -> 4 blocks/CU.
// ---------------------------------------------------------------------------
#define ROWS 22            // 16 + 2*3 halo
#define SSTR 132           // padded row stride (floats), 16B-aligned
#define SC(c, r) ((((c) * ROWS) + (r)) * SSTR)

template <bool FIRST>
__global__ __launch_bounds__(256) void forces_xy_kernel(const float* __restrict__ wpd,
                                                        const float* __restrict__ fix,
                                                        const float* __restrict__ vf,
                                                        float* __restrict__ u2) {
    int b = blockIdx.x;          // 1024 blocks
    int z = b & 127;
    int y0 = (b >> 7) << 4;      // 0,16,...,112

    __shared__ float S[3 * ROWS * SSTR];

    // ---- Stage A: forces (one eval/voxel, all channels) -> S
    for (int e = threadIdx.x; e < ROWS * 32; e += 256) {
        int x4 = e & 31;
        int r  = e >> 5;
        int gy = y0 + r - 3;
        float4 rz = make_float4(0, 0, 0, 0);
        float4 ry = make_float4(0, 0, 0, 0);
        float4 rx = make_float4(0, 0, 0, 0);
        if (gy >= 0 && gy < 128) {
            int idx = (z << 14) + (gy << 7) + (x4 << 2);
            int xb = x4 << 2;

            float4 wc4 = *(const float4*)(wpd + idx);
            float4 fc4 = *(const float4*)(fix + idx);

            int iyp = (gy < 127) ? idx + 128   : idx;
            int iym = (gy > 0)   ? idx - 128   : idx;
            int izp = (z < 127)  ? idx + 16384 : idx;
            int izm = (z > 0)    ? idx - 16384 : idx;

            float4 wyp = *(const float4*)(wpd + iyp), wym = *(const float4*)(wpd + iym);
            float4 wzp = *(const float4*)(wpd + izp), wzm = *(const float4*)(wpd + izm);
            float4 fyp = *(const float4*)(fix + iyp), fym = *(const float4*)(fix + iym);
            float4 fzp = *(const float4*)(fix + izp), fzm = *(const float4*)(fix + izm);

            float wl = (xb > 0)   ? wpd[idx - 1] : 0.0f;
            float wr = (xb < 124) ? wpd[idx + 4] : 0.0f;
            float fl = (xb > 0)   ? fix[idx - 1] : 0.0f;
            float fr = (xb < 124) ? fix[idx + 4] : 0.0f;

            float wcv[4] = {wc4.x, wc4.y, wc4.z, wc4.w};
            float fcv[4] = {fc4.x, fc4.y, fc4.z, fc4.w};
            float wypv[4] = {wyp.x, wyp.y, wyp.z, wyp.w};
            float wymv[4] = {wym.x, wym.y, wym.z, wym.w};
            float wzpv[4] = {wzp.x, wzp.y, wzp.z, wzp.w};
            float wzmv[4] = {wzm.x, wzm.y, wzm.z, wzm.w};
            float fypv[4] = {fyp.x, fyp.y, fyp.z, fyp.w};
            float fymv[4] = {fym.x, fym.y, fym.z, fym.w};
            float fzpv[4] = {fzp.x, fzp.y, fzp.z, fzp.w};
            float fzmv[4] = {fzm.x, fzm.y, fzm.z, fzm.w};

            float4 vz4 = FIRST ? make_float4(0, 0, 0, 0) : *(const float4*)(vf + idx);
            float4 vy4 = FIRST ? make_float4(0, 0, 0, 0) : *(const float4*)(vf + N + idx);
            float4 vx4 = FIRST ? make_float4(0, 0, 0, 0) : *(const float4*)(vf + 2 * N + idx);
            float vzv[4] = {vz4.x, vz4.y, vz4.z, vz4.w};
            float vyv[4] = {vy4.x, vy4.y, vy4.z, vy4.w};
            float vxv[4] = {vx4.x, vx4.y, vx4.z, vx4.w};

            float ozv[4], oyv[4], oxv[4];
#pragma unroll
            for (int i = 0; i < 4; ++i) {
                float wc = wcv[i], fc = fcv[i];
                float diff = wc - fc;

                float gwz = (z == 0)   ? (wzpv[i] - wc)
                          : (z == 127) ? (wc - wzmv[i])
                          : 0.5f * (wzpv[i] - wzmv[i]);
                float gfz = (z == 0)   ? (fzpv[i] - fc)
                          : (z == 127) ? (fc - fzmv[i])
                          : 0.5f * (fzpv[i] - fzmv[i]);
                float grz = 0.5f * (gwz + gfz);

                float gwy = (gy == 0)   ? (wypv[i] - wc)
                          : (gy == 127) ? (wc - wymv[i])
                          : 0.5f * (wypv[i] - wymv[i]);
                float gfy = (gy == 0)   ? (fypv[i] - fc)
                          : (gy == 127) ? (fc - fymv[i])
                          : 0.5f * (fypv[i] - fymv[i]);
                float gry = 0.5f * (gwy + gfy);

                float wleft  = (i == 0) ? wl : wcv[i - 1];
                float wright = (i == 3) ? wr : wcv[i + 1];
                float fleft  = (i == 0) ? fl : fcv[i - 1];
                float fright = (i == 3) ? fr : fcv[i + 1];
                int xi = xb + i;
                float gwx = (xi == 0)   ? (wright - wc)
                          : (xi == 127) ? (wc - wleft)
                          : 0.5f * (wright - wleft);
                float gfx = (xi == 0)   ? (fright - fc)
                          : (xi == 127) ? (fc - fleft)
                          : 0.5f * (fright - fleft);
                float grx = 0.5f * (gwx + gfx);

                float denom = grz * grz + gry * gry + grx * grx + diff * diff;
                float s = (denom > EPS) ? (diff / denom) : 0.0f;
                ozv[i] = vzv[i] + s * grz;
                oyv[i] = vyv[i] + s * gry;
                oxv[i] = vxv[i] + s * grx;
            }
            rz = make_float4(ozv[0], ozv[1], ozv[2], ozv[3]);
            ry = make_float4(oyv[0], oyv[1], oyv[2], oyv[3]);
            rx = make_float4(oxv[0], oxv[1], oxv[2], oxv[3]);
        }
        *(float4*)(S + SC(0, r) + (x4 << 2)) = rz;
        *(float4*)(S + SC(1, r) + (x4 << 2)) = ry;
        *(float4*)(S + SC(2, r) + (x4 << 2)) = rx;
    }
    __syncthreads();

    // ---- Stage B: x-blur, register-held in-place rewrite of S
    float4 xb[3][3];   // [unrolled e-iter][channel]
#pragma unroll
    for (int it = 0; it < 3; ++it) {
        int e = threadIdx.x + it * 256;
        if (e < ROWS * 32) {
            int x4 = e & 31;
            int r  = e >> 5;
#pragma unroll
            for (int c = 0; c < 3; ++c) {
                const float* base = S + SC(c, r) + (x4 << 2);
                float4 v0 = *(const float4*)base;
                float4 m1 = (x4 > 0)  ? *(const float4*)(base - 4) : make_float4(0, 0, 0, 0);
                float4 p1 = (x4 < 31) ? *(const float4*)(base + 4) : make_float4(0, 0, 0, 0);
                float w[12] = {m1.x, m1.y, m1.z, m1.w,
                               v0.x, v0.y, v0.z, v0.w,
                               p1.x, p1.y, p1.z, p1.w};
                float o[4];
#pragma unroll
                for (int i = 0; i < 4; ++i) {
                    o[i] = W3 * (w[i + 1] + w[i + 7]) + W2 * (w[i + 2] + w[i + 6])
                         + W1 * (w[i + 3] + w[i + 5]) + W0 * w[i + 4];
                }
                xb[it][c] = make_float4(o[0], o[1], o[2], o[3]);
            }
        }
    }
    __syncthreads();
#pragma unroll
    for (int it = 0; it < 3; ++it) {
        int e = threadIdx.x + it * 256;
        if (e < ROWS * 32) {
            int x4 = e & 31;
            int r  = e >> 5;
#pragma unroll
            for (int c = 0; c < 3; ++c)
                *(float4*)(S + SC(c, r) + (x4 << 2)) = xb[it][c];
        }
    }
    __syncthreads();

    // ---- Stage C: y-blur S -> global u2 (16 rows x 32 float4 x 3 ch)
    for (int e = threadIdx.x; e < 16 * 32 * 3; e += 256) {
        int x4 = e & 31;
        int t2 = e >> 5;
        int y  = t2 & 15;
        int c  = t2 >> 4;
        const float* base = S + SC(c, y) + (x4 << 2);   // rows y..y+6 (halo offset)
        float4 v0 = *(const float4*)(base);
        float4 v1 = *(const float4*)(base + 1 * SSTR);
        float4 v2 = *(const float4*)(base + 2 * SSTR);
        float4 v3 = *(const float4*)(base + 3 * SSTR);
        float4 v4 = *(const float4*)(base + 4 * SSTR);
        float4 v5 = *(const float4*)(base + 5 * SSTR);
        float4 v6 = *(const float4*)(base + 6 * SSTR);
        float4 acc;
        acc.x = W3 * (v0.x + v6.x) + W2 * (v1.x + v5.x) + W1 * (v2.x + v4.x) + W0 * v3.x;
        acc.y = W3 * (v0.y + v6.y) + W2 * (v1.y + v5.y) + W1 * (v2.y + v4.y) + W0 * v3.y;
        acc.z = W3 * (v0.z + v6.z) + W2 * (v1.z + v5.z) + W1 * (v2.z + v4.z) + W0 * v3.z;
        acc.w = W3 * (v0.w + v6.w) + W2 * (v1.w + v5.w) + W1 * (v2.w + v4.w) + W0 * v3.w;
        *(float4*)(u2 + (size_t)c * N + ((size_t)z << 14) + ((y0 + y) << 7) + (x4 << 2)) = acc;
    }
}

// ---------------------------------------------------------------------------
// Fused z-blur + (next iteration's) trilinear warp. One thread owns an (x,y)
// column x 8-z chunk for ALL 3 channels (8-z: 1024 blocks = 4/CU vs R7's
// 512 = 2/CU; halo amp 14/8 = 1.75 absorbed by L2/L3). 3x14-tap register
// windows -> 24 blurred vf values -> write vf; then warp those 8 voxels
// (vf in registers - no global re-read) -> write warped. DO_WARP=false on
// the final iteration.
// ---------------------------------------------------------------------------
template <bool DO_WARP>
__global__ __launch_bounds__(256) void zblur_warp_kernel(const float* __restrict__ u2,
                                                         const float* __restrict__ mov,
                                                         float* __restrict__ vf,
                                                         float* __restrict__ warped) {
    int g = blockIdx.x * 256 + threadIdx.x;   // 0 .. 262143
    int col = g & 16383;                      // (y<<7)|x
    int zc  = g >> 14;                        // 0..15
    int z0  = zc << 3;
    int x = col & 127, y = col >> 7;

    float bz[3][8];
#pragma unroll
    for (int c = 0; c < 3; ++c) {
        const float* inp = u2 + (size_t)c * N + col;
        float win[14];
#pragma unroll
        for (int i = 0; i < 14; ++i) {
            int zz = z0 - 3 + i;
            win[i] = (zz >= 0 && zz < 128) ? inp[(size_t)zz << 14] : 0.0f;
        }
#pragma unroll
        for (int k = 0; k < 8; ++k) {
            bz[c][k] = W3 * (win[k] + win[k + 6]) + W2 * (win[k + 1] + win[k + 5])
                     + W1 * (win[k + 2] + win[k + 4]) + W0 * win[k + 3];
        }
        float* outp = vf + (size_t)c * N + col;
#pragma unroll
        for (int k = 0; k < 8; ++k)
            outp[(size_t)(z0 + k) << 14] = bz[c][k];
    }

    if (DO_WARP) {
        for (int k = 0; k < 8; ++k) {
            int z = z0 + k;
            float cz = (float)z + bz[0][k];
            float cy = (float)y + bz[1][k];
            float cx = (float)x + bz[2][k];

            float flz = floorf(cz), fly = floorf(cy), flx = floorf(cx);
            float fz = cz - flz, fy = cy - fly, fx = cx - flx;

            int zi = (int)flz, yi = (int)fly, xi = (int)flx;
            int z0c = clamp_i(zi, 0, DIM - 1), z1c = clamp_i(zi + 1, 0, DIM - 1);
            int y0c = clamp_i(yi, 0, DIM - 1), y1c = clamp_i(yi + 1, 0, DIM - 1);
            int x0c = clamp_i(xi, 0, DIM - 1), x1c = clamp_i(xi + 1, 0, DIM - 1);

            int b00 = (z0c << 14) + (y0c << 7);
            int b01 = (z0c << 14) + (y1c << 7);
            int b10 = (z1c << 14) + (y0c << 7);
            int b11 = (z1c << 14) + (y1c << 7);

            float v000 = mov[b00 + x0c], v001 = mov[b00 + x1c];
            float v010 = mov[b01 + x0c], v011 = mov[b01 + x1c];
            float v100 = mov[b10 + x0c], v101 = mov[b10 + x1c];
            float v110 = mov[b11 + x0c], v111 = mov[b11 + x1c];

            float c00 = v000 + fx * (v001 - v000);
            float c01 = v010 + fx * (v011 - v010);
            float c10 = v100 + fx * (v101 - v100);
            float c11 = v110 + fx * (v111 - v110);
            float c0 = c00 + fy * (c01 - c00);
            float c1 = c10 + fy * (c11 - c10);
            warped[((size_t)z << 14) + col] = c0 + fz * (c1 - c0);
        }
    }
}

extern "C" void kernel_launch(void* const* d_in, const int* in_sizes, int n_in,
                              void* d_out, int out_size, void* d_ws, size_t ws_size,
                              hipStream_t stream) {
    const float* mov = (const float*)d_in[0];
    const float* fix = (const float*)d_in[1];
    float* vf = (float*)d_out;          // (3, N) — lives in d_out throughout
    float* ws = (float*)d_ws;
    float* warped = ws;                 // N floats
    float* u2     = ws + (size_t)N;     // 3N floats (xy-blurred forces)

    const int BLK = 256;
    const int gridFX = 128 * 8;            // 1024 (z-plane x y-strip)
    const int gridZW = (N / 8) / BLK;      // 1024

    // Iteration 1: vf==0 => warped==moving (use mov directly); zblur_warp
    // fully writes vf, so no memset of d_out is needed.
    forces_xy_kernel<true><<<gridFX, BLK, 0, stream>>>(mov, fix, nullptr, u2);
    zblur_warp_kernel<true><<<gridZW, BLK, 0, stream>>>(u2, mov, vf, warped);

    for (int it = 1; it < ITERS - 1; ++it) {
        forces_xy_kernel<false><<<gridFX, BLK, 0, stream>>>(warped, fix, vf, u2);
        zblur_warp_kernel<true><<<gridZW, BLK, 0, stream>>>(u2, mov, vf, warped);
    }
    // Final iteration: no warp needed (result unused).
    forces_xy_kernel<false><<<gridFX, BLK, 0, stream>>>(warped, fix, vf, u2);
    zblur_warp_kernel<false><<<gridZW, BLK, 0, stream>>>(u2, mov, vf, warped);
}